// Round 19
// baseline (181.968 us; speedup 1.0000x reference)
//
#include <hip/hip_runtime.h>

typedef unsigned short u16;
typedef unsigned int   u32;
typedef __bf16 bf16x8 __attribute__((ext_vector_type(8)));
typedef float  f32x4  __attribute__((ext_vector_type(4)));

__device__ __forceinline__ float bf2f(u16 h){
  u32 u = ((u32)h) << 16;
  return __builtin_bit_cast(float, u);
}
__device__ __forceinline__ u16 f2bf(float f){
  u32 u = __builtin_bit_cast(u32, f);
  u32 lsb = (u >> 16) & 1u;
  u += 0x7fffu + lsb;            // RNE
  return (u16)(u >> 16);
}
__device__ __forceinline__ float bflo(u32 u){ return __builtin_bit_cast(float, u << 16); }
__device__ __forceinline__ float bfhi(u32 u){ return __builtin_bit_cast(float, u & 0xffff0000u); }

#define AS3(p) ((__attribute__((address_space(3))) void*)(p))
#define AS1(p) ((const __attribute__((address_space(1))) void*)(p))

// ---------------- K0: fused f32 -> bf16 convert (x | w_qkv | w_proj) ----------
__global__ __launch_bounds__(256) void cvt_all(const float* __restrict__ x,  u16* __restrict__ xd,
                                               const float* __restrict__ wq, u16* __restrict__ wqd,
                                               const float* __restrict__ wp, u16* __restrict__ wpd){
  int blk = blockIdx.x;
  const float* s; u16* d; int i;
  if (blk < 8192){ s = x;  d = xd;  i = (blk * 256 + threadIdx.x) * 8; }
  else if (blk < 8288){ s = wq; d = wqd; i = ((blk - 8192) * 256 + threadIdx.x) * 8; }
  else { s = wp; d = wpd; i = ((blk - 8288) * 256 + threadIdx.x) * 8; }
  float4 a = *(const float4*)(s + i);
  float4 b = *(const float4*)(s + i + 4);
  u32 o0 = (u32)f2bf(a.x) | ((u32)f2bf(a.y) << 16);
  u32 o1 = (u32)f2bf(a.z) | ((u32)f2bf(a.w) << 16);
  u32 o2 = (u32)f2bf(b.x) | ((u32)f2bf(b.y) << 16);
  u32 o3 = (u32)f2bf(b.z) | ((u32)f2bf(b.w) << 16);
  *(uint4*)(d + i) = make_uint4(o0, o1, o2, o3);
}

// ---------------- K1: 128x128 bf16 B^T GEMM, K=256 (r13 best, ledger closed) --
// XCD-aware swizzle: lb = (bid&7)*384 + bid>>3  (3072 wg / 8 XCDs)
__global__ __launch_bounds__(256) void gemm_qkv(
  const u16* __restrict__ A, const u16* __restrict__ Bm, char* __restrict__ outp)
{
  constexpr int K = 256;
  __shared__ __align__(16) char lds[65536];   // 2 bufs x (A 16KB + B 16KB)
  const int bid0 = blockIdx.x;
  const int bid = ((bid0 & 7) * 384) + (bid0 >> 3);
  const int tn = bid % 6, tm = bid / 6;
  const int m0 = tm * 128, n0 = tn * 128;
  const int tid  = threadIdx.x;
  const int lane = tid & 63, wid = tid >> 6;
  const int wm = (wid >> 1) * 64, wn = (wid & 1) * 64;
  const int l15 = lane & 15, l16 = lane >> 4;

  auto stage = [&](int buf, int kt){
    char* la = lds + buf * 32768;
    char* lb = la + 16384;
#pragma unroll
    for (int it = 0; it < 4; ++it){
      int ch  = it * 256 + tid;         // 16B chunk id
      int row = ch >> 3;
      int k8  = (ch & 7) ^ (row & 7);   // pre-swizzled global source (LDS linear)
      __builtin_amdgcn_global_load_lds(AS1(A  + (size_t)(m0 + row) * K + kt * 64 + k8 * 8),
                                       AS3(la + ch * 16), 16, 0, 0);
      __builtin_amdgcn_global_load_lds(AS1(Bm + (size_t)(n0 + row) * K + kt * 64 + k8 * 8),
                                       AS3(lb + ch * 16), 16, 0, 0);
    }
  };

  f32x4 acc[4][4];
#pragma unroll
  for (int i = 0; i < 4; ++i)
#pragma unroll
    for (int j = 0; j < 4; ++j) acc[i][j] = (f32x4){0.f, 0.f, 0.f, 0.f};

  stage(0, 0);
  __syncthreads();
  constexpr int NT = K / 64;
  for (int kt = 0; kt < NT; ++kt){
    const int buf = kt & 1;
    if (kt + 1 < NT) stage(buf ^ 1, kt + 1);
    const char* la = lds + buf * 32768;
    const char* lb = la + 16384;
#pragma unroll
    for (int kk = 0; kk < 2; ++kk){
      bf16x8 af[4], bfr[4];
      const int ka = kk * 4 + l16;
#pragma unroll
      for (int f = 0; f < 4; ++f){
        int ra = wm + f * 16 + l15;
        af[f]  = *(const bf16x8*)(la + ra * 128 + (((ka ^ ra) & 7) << 4));
        int rb = wn + f * 16 + l15;
        bfr[f] = *(const bf16x8*)(lb + rb * 128 + (((ka ^ rb) & 7) << 4));
      }
#pragma unroll
      for (int fm = 0; fm < 4; ++fm)
#pragma unroll
        for (int fn = 0; fn < 4; ++fn)
          acc[fm][fn] = __builtin_amdgcn_mfma_f32_16x16x32_bf16(bfr[fn], af[fm], acc[fm][fn], 0, 0, 0);
    }
    __syncthreads();
  }

#pragma unroll
  for (int fm = 0; fm < 4; ++fm)
#pragma unroll
    for (int fn = 0; fn < 4; ++fn){
      int m = m0 + wm + fm * 16 + l15;
      int n = n0 + wn + fn * 16 + l16 * 4;
      u32 lo = (u32)f2bf(acc[fm][fn][0]) | ((u32)f2bf(acc[fm][fn][1]) << 16);
      u32 hi = (u32)f2bf(acc[fm][fn][2]) | ((u32)f2bf(acc[fm][fn][3]) << 16);
      int s = n >> 8, hd = (n >> 5) & 7, cc = n & 31;
      int bb = m >> 12, tok = m & 4095;
      u16* dst = (u16*)(outp + (size_t)s * 33554432u);
      *(uint2*)(dst + ((size_t)(bb * 8 + hd) * 4096 + tok) * 32 + cc) = make_uint2(lo, hi);
    }
}

// ---------------- K2: FUSED crpe + exp(k)^T v partial, per (bh, 256-token) ----
// Grid 2048 = 128 bh x 16 sp; tokens [sp*256, +256) = image rows y0..y0+3.
// Phase A: stage V bf16 halo (shared by conv AND kv MAC). Phase B: crpe -> regs.
// Phase C: kv loop (K global, V from LDS). Phase D: write pkv/pden/tmp.
// tmp aliases Kb: this block's tmp bytes == this block's (private) K bytes,
// written only after the loop's final barrier (all K loads done). No x-block overlap.
__global__ __launch_bounds__(256) void kv_crpe(
  const u16* __restrict__ Qb, const u16* __restrict__ Kb, const u16* __restrict__ Vb,
  const float* __restrict__ cw, float* __restrict__ pkv, float* __restrict__ pden,
  u16* __restrict__ tmp){
  __shared__ u16 VsB[6][66][32];   // 25344B: V halo rows y0-1..y0+4, x 0..65 (pad=0)
  __shared__ float E[64][32];      // 8KB: exp(K) per 64-token chunk
  const int bh = blockIdx.x >> 4, sp = blockIdx.x & 15;
  const int y0 = sp * 4;
  const int tid = threadIdx.x;
  const int x = tid & 63, yi = tid >> 6;
  const int n = (y0 + yi) * 64 + x;

  // --- Phase A: stage V halo (8ch-granular XOR swizzle g8^=(xc>>1)&3) ---
  for (int idx = tid; idx < 1584; idx += 256){
    int g8 = idx & 3, t2 = idx >> 2;
    int j  = t2 / 66, xc = t2 - j * 66;
    int gy = y0 - 1 + j, gx = xc - 1;
    uint4 v = make_uint4(0u, 0u, 0u, 0u);
    if ((unsigned)gy < 64u && (unsigned)gx < 64u)
      v = *(const uint4*)(Vb + ((size_t)bh * 4096 + gy * 64 + gx) * 32 + g8 * 8);
    *(uint4*)&VsB[j][xc][8 * (g8 ^ ((xc >> 1) & 3))] = v;
  }
  __syncthreads();

  // --- Phase B: crpe = q * depthwise3x3(v) -> ou[16] (held in regs) ---
  float ca[32];
#pragma unroll
  for (int i = 0; i < 32; ++i) ca[i] = 0.f;
  const int hd = bh & 7;
  const float* wp = cw + hd * 288;
#pragma unroll
  for (int tap = 0; tap < 9; ++tap){
    const int j  = yi + tap / 3;
    const int xs = x + (tap % 3);
    const u16* vrow = &VsB[j][xs][0];
    const int swz = (xs >> 1) & 3;
#pragma unroll
    for (int g8 = 0; g8 < 4; ++g8){
      uint4 q4 = *(const uint4*)(vrow + 8 * (g8 ^ swz));
      const int c0 = g8 * 8;
      ca[c0+0] += wp[(c0+0)*9+tap] * bflo(q4.x);
      ca[c0+1] += wp[(c0+1)*9+tap] * bfhi(q4.x);
      ca[c0+2] += wp[(c0+2)*9+tap] * bflo(q4.y);
      ca[c0+3] += wp[(c0+3)*9+tap] * bfhi(q4.y);
      ca[c0+4] += wp[(c0+4)*9+tap] * bflo(q4.z);
      ca[c0+5] += wp[(c0+5)*9+tap] * bfhi(q4.z);
      ca[c0+6] += wp[(c0+6)*9+tap] * bflo(q4.w);
      ca[c0+7] += wp[(c0+7)*9+tap] * bfhi(q4.w);
    }
  }
  u32 ou[16];
  {
    const u16* qrow = Qb + ((size_t)bh * 4096 + n) * 32;
    uint4 u0 = *(const uint4*)(qrow);
    uint4 u1 = *(const uint4*)(qrow + 8);
    uint4 u2 = *(const uint4*)(qrow + 16);
    uint4 u3 = *(const uint4*)(qrow + 24);
    float qf[32];
#define UQ(u, o) qf[o] = bflo(u); qf[(o)+1] = bfhi(u);
    UQ(u0.x, 0)  UQ(u0.y, 2)  UQ(u0.z, 4)  UQ(u0.w, 6)
    UQ(u1.x, 8)  UQ(u1.y, 10) UQ(u1.z, 12) UQ(u1.w, 14)
    UQ(u2.x, 16) UQ(u2.y, 18) UQ(u2.z, 20) UQ(u2.w, 22)
    UQ(u3.x, 24) UQ(u3.y, 26) UQ(u3.z, 28) UQ(u3.w, 30)
#undef UQ
#pragma unroll
    for (int p = 0; p < 16; ++p){
      float v0 = qf[2 * p]     * ca[2 * p];
      float v1 = qf[2 * p + 1] * ca[2 * p + 1];
      ou[p] = (u32)f2bf(v0) | ((u32)f2bf(v1) << 16);
    }
  }

  // --- Phase C: kv partial over 4 chunks of 64 tokens (V from VsB) ---
  const u16* kp = Kb + ((size_t)bh * 4096 + sp * 256) * 32;
  const int c = tid & 31, g = tid >> 5;
  const int srow = tid >> 2, scol = (tid & 3) * 8;
  float a0 = 0.f, a1 = 0.f, a2 = 0.f, a3 = 0.f, den = 0.f;
  for (int chx = 0; chx < 4; ++chx){
    uint4 kb4 = *(const uint4*)(kp + chx * 2048 + tid * 8);
    float4 e0, e1;
    e0.x = __expf(bflo(kb4.x)); e0.y = __expf(bfhi(kb4.x));
    e0.z = __expf(bflo(kb4.y)); e0.w = __expf(bfhi(kb4.y));
    e1.x = __expf(bflo(kb4.z)); e1.y = __expf(bfhi(kb4.z));
    e1.z = __expf(bflo(kb4.w)); e1.w = __expf(bfhi(kb4.w));
    *(float4*)&E[srow][scol]     = e0;
    *(float4*)&E[srow][scol + 4] = e1;
    __syncthreads();
    const int j = chx + 1;                       // VsB row for tokens of this chunk
    const int goff = (g & 1) * 4;                // position within 8ch group
    const int G8 = g >> 1;
#pragma unroll 4
    for (int nn = 0; nn < 64; ++nn){
      float e = E[nn][c];
      int xc = nn + 1;
      const u16* vp4 = &VsB[j][xc][8 * (G8 ^ ((xc >> 1) & 3)) + goff];
      uint2 vv = *(const uint2*)vp4;             // 4 bf16, broadcast within lane-group
      a0 += e * bflo(vv.x); a1 += e * bfhi(vv.x);
      a2 += e * bflo(vv.y); a3 += e * bfhi(vv.y);
      den += e;
    }
    __syncthreads();                             // protect E overwrite; last iter: all K loads done
  }

  // --- Phase D: outputs (tmp overwrite of this block's K bytes is now safe) ---
  size_t base = ((size_t)sp * 128 + bh) * 1024 + (size_t)c * 32 + g * 4;
  *(float4*)&pkv[base] = make_float4(a0, a1, a2, a3);
  if (g == 0) pden[((size_t)sp * 128 + bh) * 32 + c] = den;
  uint4* dst = (uint4*)(tmp + ((size_t)bh * 4096 + n) * 32);   // plane layout
  dst[0] = make_uint4(ou[0],  ou[1],  ou[2],  ou[3]);
  dst[1] = make_uint4(ou[4],  ou[5],  ou[6],  ou[7]);
  dst[2] = make_uint4(ou[8],  ou[9],  ou[10], ou[11]);
  dst[3] = make_uint4(ou[12], ou[13], ou[14], ou[15]);
}

// ---------------- K3: reduce 16 splits + normalize + fold scale + build W2T ---
__global__ __launch_bounds__(256) void kv_w2(const float* __restrict__ pkv, const float* __restrict__ pden,
                                             const float* __restrict__ wproj, u16* __restrict__ w2t){
  __shared__ float kv[1024];
  __shared__ float dn[32];
  const int bh = blockIdx.x, b = bh >> 3, hd = bh & 7;
  const int t = threadIdx.x;
  if (t < 32){
    float d = 0.f;
#pragma unroll
    for (int s = 0; s < 16; ++s) d += pden[((size_t)s * 128 + bh) * 32 + t];
    dn[t] = 0.17677669529663687f / d;   // scale = 32^-0.5 folded
  }
  __syncthreads();
#pragma unroll
  for (int i = 0; i < 4; ++i){
    int idx = t + i * 256;
    float v = 0.f;
#pragma unroll
    for (int s = 0; s < 16; ++s) v += pkv[((size_t)s * 128 + bh) * 1024 + idx];
    kv[idx] = v * dn[idx >> 5];
  }
  __syncthreads();
  float wr[32];
  const float* wp = wproj + (size_t)t * 256 + hd * 32;
#pragma unroll
  for (int j = 0; j < 8; ++j){
    float4 w4 = ((const float4*)wp)[j];
    wr[j*4] = w4.x; wr[j*4+1] = w4.y; wr[j*4+2] = w4.z; wr[j*4+3] = w4.w;
  }
  u32 ou[16];
#pragma unroll
  for (int c = 0; c < 32; ++c){
    float acc = 0.f;
#pragma unroll
    for (int v4 = 0; v4 < 8; ++v4){
      float4 kk = *(const float4*)&kv[c * 32 + v4 * 4];   // uniform addr -> broadcast
      acc += kk.x * wr[v4*4] + kk.y * wr[v4*4+1] + kk.z * wr[v4*4+2] + kk.w * wr[v4*4+3];
    }
    if (c & 1) ou[c >> 1] |= (u32)f2bf(acc) << 16; else ou[c >> 1] = f2bf(acc);
  }
  uint4* dst = (uint4*)(w2t + (size_t)b * 65536 + (size_t)t * 256 + hd * 32);
  dst[0] = make_uint4(ou[0],  ou[1],  ou[2],  ou[3]);
  dst[1] = make_uint4(ou[4],  ou[5],  ou[6],  ou[7]);
  dst[2] = make_uint4(ou[8],  ou[9],  ou[10], ou[11]);
  dst[3] = make_uint4(ou[12], ou[13], ou[14], ou[15]);
}

// ---------------- K4: final GEMM, K=512: out = [crpe | q] @ [Wp^T ; W2[b]] + bias
// XCD-aware swizzle: lb = (bid&7)*128 + bid>>3  (1024 wg / 8 XCDs)
__global__ __launch_bounds__(256) void gemm_fin(
  const u16* __restrict__ Acr, const u16* __restrict__ Qb,
  const u16* __restrict__ Bw,  const u16* __restrict__ W2t,
  float* __restrict__ outp, const float* __restrict__ bias)
{
  __shared__ __align__(16) char lds[65536];
  const int bid0 = blockIdx.x;
  const int bid = ((bid0 & 7) * 128) + (bid0 >> 3);
  const int tn = bid & 1, tm = bid >> 1;
  const int m0 = tm * 128, n0 = tn * 128;
  const int b = m0 >> 12, nbase = m0 & 4095;
  const int tid  = threadIdx.x;
  const int lane = tid & 63, wid = tid >> 6;
  const int wm = (wid >> 1) * 64, wn = (wid & 1) * 64;
  const int l15 = lane & 15, l16 = lane >> 4;

  auto stage = [&](int buf, int kt){
    char* la = lds + buf * 32768;
    char* lb = la + 16384;
#pragma unroll
    for (int it = 0; it < 4; ++it){
      int ch  = it * 256 + tid;
      int row = ch >> 3;
      int k8  = (ch & 7) ^ (row & 7);
      int kp  = kt * 64 + k8 * 8;         // 0..511
      const u16* pl = (kp < 256) ? Acr : Qb;
      int kq = kp & 255, hd = kq >> 5, cc = kq & 31;
      const u16* asrc = pl + ((size_t)(b * 8 + hd) * 4096 + (nbase + row)) * 32 + cc;
      const u16* bsrc = (kp < 256)
        ? Bw  + (size_t)(n0 + row) * 256 + kp
        : W2t + (size_t)b * 65536 + (size_t)(n0 + row) * 256 + (kp - 256);
      __builtin_amdgcn_global_load_lds(AS1(asrc), AS3(la + ch * 16), 16, 0, 0);
      __builtin_amdgcn_global_load_lds(AS1(bsrc), AS3(lb + ch * 16), 16, 0, 0);
    }
  };

  f32x4 acc[4][4];
#pragma unroll
  for (int i = 0; i < 4; ++i)
#pragma unroll
    for (int j = 0; j < 4; ++j) acc[i][j] = (f32x4){0.f, 0.f, 0.f, 0.f};

  stage(0, 0);
  __syncthreads();
  constexpr int NT = 8;   // K = 512
  for (int kt = 0; kt < NT; ++kt){
    const int buf = kt & 1;
    if (kt + 1 < NT) stage(buf ^ 1, kt + 1);
    const char* la = lds + buf * 32768;
    const char* lb = la + 16384;
#pragma unroll
    for (int kk = 0; kk < 2; ++kk){
      bf16x8 af[4], bfr[4];
      const int ka = kk * 4 + l16;
#pragma unroll
      for (int f = 0; f < 4; ++f){
        int ra = wm + f * 16 + l15;
        af[f]  = *(const bf16x8*)(la + ra * 128 + (((ka ^ ra) & 7) << 4));
        int rb = wn + f * 16 + l15;
        bfr[f] = *(const bf16x8*)(lb + rb * 128 + (((ka ^ rb) & 7) << 4));
      }
#pragma unroll
      for (int fm = 0; fm < 4; ++fm)
#pragma unroll
        for (int fn = 0; fn < 4; ++fn)
          acc[fm][fn] = __builtin_amdgcn_mfma_f32_16x16x32_bf16(af[fm], bfr[fn], acc[fm][fn], 0, 0, 0);
    }
    __syncthreads();
  }

#pragma unroll
  for (int fm = 0; fm < 4; ++fm)
#pragma unroll
    for (int fn = 0; fn < 4; ++fn)
#pragma unroll
      for (int r = 0; r < 4; ++r){
        int m = m0 + wm + fm * 16 + l16 * 4 + r;
        int n = n0 + wn + fn * 16 + l15;
        outp[(size_t)m * 256 + n] = acc[fm][fn][r] + bias[n];
      }
}

// ---------------- launch ----------------
// ws (~111.4 MB): Qb[0,32M) Kb[32M,64M) Vb[64M,96M) wprojb(128K) pkv(8M) pden(256K) w2t(2M)
// d_out scratch: xbf(32M)@0, wqkvb(384K)@32M — both dead before gemm_fin writes d_out.
// crpe tmp aliases Kb (per-block private byte range; see kv_crpe header).
extern "C" void kernel_launch(void* const* d_in, const int* in_sizes, int n_in,
                              void* d_out, int out_size, void* d_ws, size_t ws_size,
                              hipStream_t stream) {
  const float* x      = (const float*)d_in[0];
  const float* w_qkv  = (const float*)d_in[1];
  const float* w_proj = (const float*)d_in[2];
  const float* b_proj = (const float*)d_in[3];
  const float* conv_w = (const float*)d_in[4];

  char* ws = (char*)d_ws;
  char* ob = (char*)d_out;

  char*  qkvb   =          ws;
  u16*   Qb     = (u16*)  (ws);
  u16*   Kb     = (u16*)  (ws + 33554432);
  u16*   Vb     = (u16*)  (ws + 67108864);
  u16*   wprojb = (u16*)  (ws + 100663296);     // 128KB
  float* pkv    = (float*)(ws + 100794368);     // 8MB
  float* pden   = (float*)(ws + 109182976);     // 256KB
  u16*   w2t    = (u16*)  (ws + 109445120);     // 2MB -> ends ~111.4MB

  u16*   xbf    = (u16*)  (ob);                 // 32MB scratch in d_out
  u16*   wqkvb  = (u16*)  (ob + 33554432);      // 384KB scratch in d_out
  u16*   tmp    = Kb;                           // crpe plane; aliases K (private ranges)

  cvt_all<<<8320, 256, 0, stream>>>(x, xbf, w_qkv, wqkvb, w_proj, wprojb);

  gemm_qkv<<<3072, 256, 0, stream>>>(xbf, wqkvb, qkvb);

  kv_crpe<<<2048, 256, 0, stream>>>(Qb, Kb, Vb, conv_w, pkv, pden, tmp);
  kv_w2<<<128, 256, 0, stream>>>(pkv, pden, w_proj, w2t);

  gemm_fin<<<1024, 256, 0, stream>>>(tmp, Qb, wprojb, w2t, (float*)d_out, b_proj);
}

// Round 20
// 156.160 us; speedup vs baseline: 1.1653x; 1.1653x over previous
//
#include <hip/hip_runtime.h>

typedef unsigned short u16;
typedef unsigned int   u32;
typedef __bf16 bf16x8 __attribute__((ext_vector_type(8)));
typedef float  f32x4  __attribute__((ext_vector_type(4)));

__device__ __forceinline__ float bf2f(u16 h){
  u32 u = ((u32)h) << 16;
  return __builtin_bit_cast(float, u);
}
__device__ __forceinline__ u16 f2bf(float f){
  u32 u = __builtin_bit_cast(u32, f);
  u32 lsb = (u >> 16) & 1u;
  u += 0x7fffu + lsb;            // RNE
  return (u16)(u >> 16);
}
__device__ __forceinline__ float bflo(u32 u){ return __builtin_bit_cast(float, u << 16); }
__device__ __forceinline__ float bfhi(u32 u){ return __builtin_bit_cast(float, u & 0xffff0000u); }

#define AS3(p) ((__attribute__((address_space(3))) void*)(p))
#define AS1(p) ((const __attribute__((address_space(1))) void*)(p))

// ---------------- K0: fused f32 -> bf16 convert (x | w_qkv | w_proj) ----------
__global__ __launch_bounds__(256) void cvt_all(const float* __restrict__ x,  u16* __restrict__ xd,
                                               const float* __restrict__ wq, u16* __restrict__ wqd,
                                               const float* __restrict__ wp, u16* __restrict__ wpd){
  int blk = blockIdx.x;
  const float* s; u16* d; int i;
  if (blk < 8192){ s = x;  d = xd;  i = (blk * 256 + threadIdx.x) * 8; }
  else if (blk < 8288){ s = wq; d = wqd; i = ((blk - 8192) * 256 + threadIdx.x) * 8; }
  else { s = wp; d = wpd; i = ((blk - 8288) * 256 + threadIdx.x) * 8; }
  float4 a = *(const float4*)(s + i);
  float4 b = *(const float4*)(s + i + 4);
  u32 o0 = (u32)f2bf(a.x) | ((u32)f2bf(a.y) << 16);
  u32 o1 = (u32)f2bf(a.z) | ((u32)f2bf(a.w) << 16);
  u32 o2 = (u32)f2bf(b.x) | ((u32)f2bf(b.y) << 16);
  u32 o3 = (u32)f2bf(b.z) | ((u32)f2bf(b.w) << 16);
  *(uint4*)(d + i) = make_uint4(o0, o1, o2, o3);
}

// ---------------- K1: 128x128 bf16 B^T GEMM, K=256 (ledger closed: 40.4us) ----
// XCD-aware swizzle: lb = (bid&7)*384 + bid>>3  (3072 wg / 8 XCDs)
__global__ __launch_bounds__(256) void gemm_qkv(
  const u16* __restrict__ A, const u16* __restrict__ Bm, char* __restrict__ outp)
{
  constexpr int K = 256;
  __shared__ __align__(16) char lds[65536];   // 2 bufs x (A 16KB + B 16KB)
  const int bid0 = blockIdx.x;
  const int bid = ((bid0 & 7) * 384) + (bid0 >> 3);
  const int tn = bid % 6, tm = bid / 6;
  const int m0 = tm * 128, n0 = tn * 128;
  const int tid  = threadIdx.x;
  const int lane = tid & 63, wid = tid >> 6;
  const int wm = (wid >> 1) * 64, wn = (wid & 1) * 64;
  const int l15 = lane & 15, l16 = lane >> 4;

  auto stage = [&](int buf, int kt){
    char* la = lds + buf * 32768;
    char* lb = la + 16384;
#pragma unroll
    for (int it = 0; it < 4; ++it){
      int ch  = it * 256 + tid;         // 16B chunk id
      int row = ch >> 3;
      int k8  = (ch & 7) ^ (row & 7);   // pre-swizzled global source (LDS linear)
      __builtin_amdgcn_global_load_lds(AS1(A  + (size_t)(m0 + row) * K + kt * 64 + k8 * 8),
                                       AS3(la + ch * 16), 16, 0, 0);
      __builtin_amdgcn_global_load_lds(AS1(Bm + (size_t)(n0 + row) * K + kt * 64 + k8 * 8),
                                       AS3(lb + ch * 16), 16, 0, 0);
    }
  };

  f32x4 acc[4][4];
#pragma unroll
  for (int i = 0; i < 4; ++i)
#pragma unroll
    for (int j = 0; j < 4; ++j) acc[i][j] = (f32x4){0.f, 0.f, 0.f, 0.f};

  stage(0, 0);
  __syncthreads();
  constexpr int NT = K / 64;
  for (int kt = 0; kt < NT; ++kt){
    const int buf = kt & 1;
    if (kt + 1 < NT) stage(buf ^ 1, kt + 1);
    const char* la = lds + buf * 32768;
    const char* lb = la + 16384;
#pragma unroll
    for (int kk = 0; kk < 2; ++kk){
      bf16x8 af[4], bfr[4];
      const int ka = kk * 4 + l16;
#pragma unroll
      for (int f = 0; f < 4; ++f){
        int ra = wm + f * 16 + l15;
        af[f]  = *(const bf16x8*)(la + ra * 128 + (((ka ^ ra) & 7) << 4));
        int rb = wn + f * 16 + l15;
        bfr[f] = *(const bf16x8*)(lb + rb * 128 + (((ka ^ rb) & 7) << 4));
      }
#pragma unroll
      for (int fm = 0; fm < 4; ++fm)
#pragma unroll
        for (int fn = 0; fn < 4; ++fn)
          acc[fm][fn] = __builtin_amdgcn_mfma_f32_16x16x32_bf16(bfr[fn], af[fm], acc[fm][fn], 0, 0, 0);
    }
    __syncthreads();
  }

  // swapped-C mapping: m = ...+l15, n = ...+l16*4+reg (4 consecutive n, 8B store)
#pragma unroll
  for (int fm = 0; fm < 4; ++fm)
#pragma unroll
    for (int fn = 0; fn < 4; ++fn){
      int m = m0 + wm + fm * 16 + l15;
      int n = n0 + wn + fn * 16 + l16 * 4;
      u32 lo = (u32)f2bf(acc[fm][fn][0]) | ((u32)f2bf(acc[fm][fn][1]) << 16);
      u32 hi = (u32)f2bf(acc[fm][fn][2]) | ((u32)f2bf(acc[fm][fn][3]) << 16);
      int s = n >> 8, hd = (n >> 5) & 7, cc = n & 31;
      int bb = m >> 12, tok = m & 4095;
      u16* dst = (u16*)(outp + (size_t)s * 33554432u);
      *(uint2*)(dst + ((size_t)(bb * 8 + hd) * 4096 + tok) * 32 + cc) = make_uint2(lo, hi);
    }
}

// ---------------- K2: per-(b,h) partial exp(k)^T v + denom, 16-way split ------
// r19 fusion with crpe REVERTED (92.6us: V-from-LDS bf16 unpack made it
// VALU-bound at 56%; split pair = ~43us total).
__global__ __launch_bounds__(256) void kv_partial(const u16* __restrict__ Kb, const u16* __restrict__ Vb,
                                                  float* __restrict__ pkv, float* __restrict__ pden){
  __shared__ float E [64][32];
  __shared__ float Vf[64][32];
  const int bh = blockIdx.x >> 4, sp = blockIdx.x & 15;
  const int tid = threadIdx.x;
  const u16* kp = Kb + ((size_t)bh * 4096 + sp * 256) * 32;
  const u16* vp = Vb + ((size_t)bh * 4096 + sp * 256) * 32;
  const int c = tid & 31, g = tid >> 5;
  const int srow = tid >> 2, scol = (tid & 3) * 8;
  float a0 = 0.f, a1 = 0.f, a2 = 0.f, a3 = 0.f, den = 0.f;
  for (int chx = 0; chx < 4; ++chx){
    uint4 kb4 = *(const uint4*)(kp + chx * 2048 + tid * 8);
    uint4 vb4 = *(const uint4*)(vp + chx * 2048 + tid * 8);
    float4 e0, e1, v0, v1;
    e0.x = __expf(bflo(kb4.x)); e0.y = __expf(bfhi(kb4.x));
    e0.z = __expf(bflo(kb4.y)); e0.w = __expf(bfhi(kb4.y));
    e1.x = __expf(bflo(kb4.z)); e1.y = __expf(bfhi(kb4.z));
    e1.z = __expf(bflo(kb4.w)); e1.w = __expf(bfhi(kb4.w));
    v0.x = bflo(vb4.x); v0.y = bfhi(vb4.x);
    v0.z = bflo(vb4.y); v0.w = bfhi(vb4.y);
    v1.x = bflo(vb4.z); v1.y = bfhi(vb4.z);
    v1.z = bflo(vb4.w); v1.w = bfhi(vb4.w);
    *(float4*)&E [srow][scol]     = e0;  *(float4*)&E [srow][scol + 4] = e1;
    *(float4*)&Vf[srow][scol]     = v0;  *(float4*)&Vf[srow][scol + 4] = v1;
    __syncthreads();
#pragma unroll 4
    for (int nn = 0; nn < 64; ++nn){
      float e = E[nn][c];
      float4 vv = *(const float4*)&Vf[nn][g * 4];
      a0 += e * vv.x; a1 += e * vv.y; a2 += e * vv.z; a3 += e * vv.w;
      den += e;
    }
    __syncthreads();
  }
  size_t base = ((size_t)sp * 128 + bh) * 1024 + (size_t)c * 32 + g * 4;
  *(float4*)&pkv[base] = make_float4(a0, a1, a2, a3);
  if (g == 0) pden[((size_t)sp * 128 + bh) * 32 + c] = den;
}

// ---------------- K3: reduce 16 splits + normalize + fold scale + build W2T ---
__global__ __launch_bounds__(256) void kv_w2(const float* __restrict__ pkv, const float* __restrict__ pden,
                                             const float* __restrict__ wproj, u16* __restrict__ w2t){
  __shared__ float kv[1024];
  __shared__ float dn[32];
  const int bh = blockIdx.x, b = bh >> 3, hd = bh & 7;
  const int t = threadIdx.x;
  if (t < 32){
    float d = 0.f;
#pragma unroll
    for (int s = 0; s < 16; ++s) d += pden[((size_t)s * 128 + bh) * 32 + t];
    dn[t] = 0.17677669529663687f / d;   // scale = 32^-0.5 folded
  }
  __syncthreads();
#pragma unroll
  for (int i = 0; i < 4; ++i){
    int idx = t + i * 256;
    float v = 0.f;
#pragma unroll
    for (int s = 0; s < 16; ++s) v += pkv[((size_t)s * 128 + bh) * 1024 + idx];
    kv[idx] = v * dn[idx >> 5];
  }
  __syncthreads();
  float wr[32];
  const float* wp = wproj + (size_t)t * 256 + hd * 32;
#pragma unroll
  for (int j = 0; j < 8; ++j){
    float4 w4 = ((const float4*)wp)[j];
    wr[j*4] = w4.x; wr[j*4+1] = w4.y; wr[j*4+2] = w4.z; wr[j*4+3] = w4.w;
  }
  u32 ou[16];
#pragma unroll
  for (int c = 0; c < 32; ++c){
    float acc = 0.f;
#pragma unroll
    for (int v4 = 0; v4 < 8; ++v4){
      float4 kk = *(const float4*)&kv[c * 32 + v4 * 4];   // uniform addr -> broadcast
      acc += kk.x * wr[v4*4] + kk.y * wr[v4*4+1] + kk.z * wr[v4*4+2] + kk.w * wr[v4*4+3];
    }
    if (c & 1) ou[c >> 1] |= (u32)f2bf(acc) << 16; else ou[c >> 1] = f2bf(acc);
  }
  uint4* dst = (uint4*)(w2t + (size_t)b * 65536 + (size_t)t * 256 + hd * 32);
  dst[0] = make_uint4(ou[0],  ou[1],  ou[2],  ou[3]);
  dst[1] = make_uint4(ou[4],  ou[5],  ou[6],  ou[7]);
  dst[2] = make_uint4(ou[8],  ou[9],  ou[10], ou[11]);
  dst[3] = make_uint4(ou[12], ou[13], ou[14], ou[15]);
}

// ---------------- K4: crpe = q * depthwise3x3(v), bf16 LDS + vec staging ------
__global__ __launch_bounds__(256) void attn_crpe(const u16* __restrict__ Qb, const u16* __restrict__ Vb,
                                                 const float* __restrict__ cw, u16* __restrict__ tmp){
  __shared__ u16 VsB[6][66][32];   // raw bf16, 25344B; halo y0-1..y0+4, x 0..65 (pad=0)
  const int bid = blockIdx.x;
  const int bh = bid >> 4, rbk = bid & 15;
  const int y0 = rbk * 4;
  const int tid = threadIdx.x;
  const int x = tid & 63, yi = tid >> 6;
  const int n = (y0 + yi) * 64 + x;

  for (int idx = tid; idx < 1584; idx += 256){
    int g8 = idx & 3, t2 = idx >> 2;
    int j  = t2 / 66, xc = t2 - j * 66;
    int gy = y0 - 1 + j, gx = xc - 1;
    uint4 v = make_uint4(0u, 0u, 0u, 0u);
    if ((unsigned)gy < 64u && (unsigned)gx < 64u)
      v = *(const uint4*)(Vb + ((size_t)bh * 4096 + gy * 64 + gx) * 32 + g8 * 8);
    *(uint4*)&VsB[j][xc][8 * (g8 ^ ((xc >> 1) & 3))] = v;
  }
  __syncthreads();

  float ca[32];
#pragma unroll
  for (int i = 0; i < 32; ++i) ca[i] = 0.f;
  const int hd = bh & 7;
  const float* wp = cw + hd * 288;
#pragma unroll
  for (int tap = 0; tap < 9; ++tap){
    const int j  = yi + tap / 3;
    const int xs = x + (tap % 3);
    const u16* vrow = &VsB[j][xs][0];
    const int swz = (xs >> 1) & 3;
#pragma unroll
    for (int g8 = 0; g8 < 4; ++g8){
      uint4 q4 = *(const uint4*)(vrow + 8 * (g8 ^ swz));
      const int c0 = g8 * 8;
      ca[c0+0] += wp[(c0+0)*9+tap] * bflo(q4.x);
      ca[c0+1] += wp[(c0+1)*9+tap] * bfhi(q4.x);
      ca[c0+2] += wp[(c0+2)*9+tap] * bflo(q4.y);
      ca[c0+3] += wp[(c0+3)*9+tap] * bfhi(q4.y);
      ca[c0+4] += wp[(c0+4)*9+tap] * bflo(q4.z);
      ca[c0+5] += wp[(c0+5)*9+tap] * bfhi(q4.z);
      ca[c0+6] += wp[(c0+6)*9+tap] * bflo(q4.w);
      ca[c0+7] += wp[(c0+7)*9+tap] * bfhi(q4.w);
    }
  }

  const u16* qrow = Qb + ((size_t)bh * 4096 + n) * 32;
  uint4 u0 = *(const uint4*)(qrow);
  uint4 u1 = *(const uint4*)(qrow + 8);
  uint4 u2 = *(const uint4*)(qrow + 16);
  uint4 u3 = *(const uint4*)(qrow + 24);
  float qf[32];
#define UQ(u, o) qf[o] = bflo(u); qf[(o)+1] = bfhi(u);
  UQ(u0.x, 0)  UQ(u0.y, 2)  UQ(u0.z, 4)  UQ(u0.w, 6)
  UQ(u1.x, 8)  UQ(u1.y, 10) UQ(u1.z, 12) UQ(u1.w, 14)
  UQ(u2.x, 16) UQ(u2.y, 18) UQ(u2.z, 20) UQ(u2.w, 22)
  UQ(u3.x, 24) UQ(u3.y, 26) UQ(u3.z, 28) UQ(u3.w, 30)
#undef UQ

  u32 ou[16];
#pragma unroll
  for (int p = 0; p < 16; ++p){
    float v0 = qf[2 * p]     * ca[2 * p];
    float v1 = qf[2 * p + 1] * ca[2 * p + 1];
    ou[p] = (u32)f2bf(v0) | ((u32)f2bf(v1) << 16);
  }
  uint4* dst = (uint4*)(tmp + ((size_t)bh * 4096 + n) * 32);   // plane layout
  dst[0] = make_uint4(ou[0],  ou[1],  ou[2],  ou[3]);
  dst[1] = make_uint4(ou[4],  ou[5],  ou[6],  ou[7]);
  dst[2] = make_uint4(ou[8],  ou[9],  ou[10], ou[11]);
  dst[3] = make_uint4(ou[12], ou[13], ou[14], ou[15]);
}

// ---------------- K5: final GEMM, K=512: out = [crpe | q] @ [Wp^T ; W2[b]] + bias
// XCD-aware swizzle: lb = (bid&7)*128 + bid>>3  (1024 wg / 8 XCDs)
__global__ __launch_bounds__(256) void gemm_fin(
  const u16* __restrict__ Acr, const u16* __restrict__ Qb,
  const u16* __restrict__ Bw,  const u16* __restrict__ W2t,
  float* __restrict__ outp, const float* __restrict__ bias)
{
  __shared__ __align__(16) char lds[65536];
  const int bid0 = blockIdx.x;
  const int bid = ((bid0 & 7) * 128) + (bid0 >> 3);
  const int tn = bid & 1, tm = bid >> 1;
  const int m0 = tm * 128, n0 = tn * 128;
  const int b = m0 >> 12, nbase = m0 & 4095;
  const int tid  = threadIdx.x;
  const int lane = tid & 63, wid = tid >> 6;
  const int wm = (wid >> 1) * 64, wn = (wid & 1) * 64;
  const int l15 = lane & 15, l16 = lane >> 4;

  auto stage = [&](int buf, int kt){
    char* la = lds + buf * 32768;
    char* lb = la + 16384;
#pragma unroll
    for (int it = 0; it < 4; ++it){
      int ch  = it * 256 + tid;
      int row = ch >> 3;
      int k8  = (ch & 7) ^ (row & 7);
      int kp  = kt * 64 + k8 * 8;         // 0..511
      const u16* pl = (kp < 256) ? Acr : Qb;
      int kq = kp & 255, hd = kq >> 5, cc = kq & 31;
      const u16* asrc = pl + ((size_t)(b * 8 + hd) * 4096 + (nbase + row)) * 32 + cc;
      const u16* bsrc = (kp < 256)
        ? Bw  + (size_t)(n0 + row) * 256 + kp
        : W2t + (size_t)b * 65536 + (size_t)(n0 + row) * 256 + (kp - 256);
      __builtin_amdgcn_global_load_lds(AS1(asrc), AS3(la + ch * 16), 16, 0, 0);
      __builtin_amdgcn_global_load_lds(AS1(bsrc), AS3(lb + ch * 16), 16, 0, 0);
    }
  };

  f32x4 acc[4][4];
#pragma unroll
  for (int i = 0; i < 4; ++i)
#pragma unroll
    for (int j = 0; j < 4; ++j) acc[i][j] = (f32x4){0.f, 0.f, 0.f, 0.f};

  stage(0, 0);
  __syncthreads();
  constexpr int NT = 8;   // K = 512
  for (int kt = 0; kt < NT; ++kt){
    const int buf = kt & 1;
    if (kt + 1 < NT) stage(buf ^ 1, kt + 1);
    const char* la = lds + buf * 32768;
    const char* lb = la + 16384;
#pragma unroll
    for (int kk = 0; kk < 2; ++kk){
      bf16x8 af[4], bfr[4];
      const int ka = kk * 4 + l16;
#pragma unroll
      for (int f = 0; f < 4; ++f){
        int ra = wm + f * 16 + l15;
        af[f]  = *(const bf16x8*)(la + ra * 128 + (((ka ^ ra) & 7) << 4));
        int rb = wn + f * 16 + l15;
        bfr[f] = *(const bf16x8*)(lb + rb * 128 + (((ka ^ rb) & 7) << 4));
      }
#pragma unroll
      for (int fm = 0; fm < 4; ++fm)
#pragma unroll
        for (int fn = 0; fn < 4; ++fn)
          acc[fm][fn] = __builtin_amdgcn_mfma_f32_16x16x32_bf16(af[fm], bfr[fn], acc[fm][fn], 0, 0, 0);
    }
    __syncthreads();
  }

#pragma unroll
  for (int fm = 0; fm < 4; ++fm)
#pragma unroll
    for (int fn = 0; fn < 4; ++fn)
#pragma unroll
      for (int r = 0; r < 4; ++r){
        int m = m0 + wm + fm * 16 + l16 * 4 + r;
        int n = n0 + wn + fn * 16 + l15;
        outp[(size_t)m * 256 + n] = acc[fm][fn][r] + bias[n];
      }
}

// ---------------- launch ----------------
// ws (~111.4 MB): Qb[0,32M) Kb[32M,64M) Vb[64M,96M) wprojb(128K) pkv(8M) pden(256K) w2t(2M)
// d_out scratch: xbf(32M)@0, wqkvb(384K)@32M — both dead before gemm_fin writes d_out.
// crpe tmp aliases Kb (plane layout; K dead after kv_partial).
extern "C" void kernel_launch(void* const* d_in, const int* in_sizes, int n_in,
                              void* d_out, int out_size, void* d_ws, size_t ws_size,
                              hipStream_t stream) {
  const float* x      = (const float*)d_in[0];
  const float* w_qkv  = (const float*)d_in[1];
  const float* w_proj = (const float*)d_in[2];
  const float* b_proj = (const float*)d_in[3];
  const float* conv_w = (const float*)d_in[4];

  char* ws = (char*)d_ws;
  char* ob = (char*)d_out;

  char*  qkvb   =          ws;
  u16*   Qb     = (u16*)  (ws);
  u16*   Kb     = (u16*)  (ws + 33554432);
  u16*   Vb     = (u16*)  (ws + 67108864);
  u16*   wprojb = (u16*)  (ws + 100663296);     // 128KB
  float* pkv    = (float*)(ws + 100794368);     // 8MB
  float* pden   = (float*)(ws + 109182976);     // 256KB
  u16*   w2t    = (u16*)  (ws + 109445120);     // 2MB -> ends ~111.4MB

  u16*   xbf    = (u16*)  (ob);                 // 32MB scratch in d_out
  u16*   wqkvb  = (u16*)  (ob + 33554432);      // 384KB scratch in d_out
  u16*   tmp    = Kb;                           // crpe plane; K dead after kv_partial

  cvt_all<<<8320, 256, 0, stream>>>(x, xbf, w_qkv, wqkvb, w_proj, wprojb);

  gemm_qkv<<<3072, 256, 0, stream>>>(xbf, wqkvb, qkvb);

  kv_partial<<<2048, 256, 0, stream>>>(Kb, Vb, pkv, pden);
  kv_w2<<<128, 256, 0, stream>>>(pkv, pden, w_proj, w2t);

  attn_crpe<<<2048, 256, 0, stream>>>(Qb, Vb, conv_w, tmp);

  gemm_fin<<<1024, 256, 0, stream>>>(tmp, Qb, wprojb, w2t, (float*)d_out, b_proj);
}

// Round 22
// 154.858 us; speedup vs baseline: 1.1751x; 1.0084x over previous
//
#include <hip/hip_runtime.h>

typedef unsigned short u16;
typedef unsigned int   u32;
typedef __bf16 bf16x8 __attribute__((ext_vector_type(8)));
typedef float  f32x4  __attribute__((ext_vector_type(4)));

__device__ __forceinline__ float bf2f(u16 h){
  u32 u = ((u32)h) << 16;
  return __builtin_bit_cast(float, u);
}
__device__ __forceinline__ u16 f2bf(float f){
  u32 u = __builtin_bit_cast(u32, f);
  u32 lsb = (u >> 16) & 1u;
  u += 0x7fffu + lsb;            // RNE
  return (u16)(u >> 16);
}
__device__ __forceinline__ float bflo(u32 u){ return __builtin_bit_cast(float, u << 16); }
__device__ __forceinline__ float bfhi(u32 u){ return __builtin_bit_cast(float, u & 0xffff0000u); }

#define AS3(p) ((__attribute__((address_space(3))) void*)(p))
#define AS1(p) ((const __attribute__((address_space(1))) void*)(p))

// ---------------- K0: fused f32 -> bf16 convert (x | w_qkv | w_proj) ----------
__global__ __launch_bounds__(256) void cvt_all(const float* __restrict__ x,  u16* __restrict__ xd,
                                               const float* __restrict__ wq, u16* __restrict__ wqd,
                                               const float* __restrict__ wp, u16* __restrict__ wpd){
  int blk = blockIdx.x;
  const float* s; u16* d; int i;
  if (blk < 8192){ s = x;  d = xd;  i = (blk * 256 + threadIdx.x) * 8; }
  else if (blk < 8288){ s = wq; d = wqd; i = ((blk - 8192) * 256 + threadIdx.x) * 8; }
  else { s = wp; d = wpd; i = ((blk - 8288) * 256 + threadIdx.x) * 8; }
  float4 a = *(const float4*)(s + i);
  float4 b = *(const float4*)(s + i + 4);
  u32 o0 = (u32)f2bf(a.x) | ((u32)f2bf(a.y) << 16);
  u32 o1 = (u32)f2bf(a.z) | ((u32)f2bf(a.w) << 16);
  u32 o2 = (u32)f2bf(b.x) | ((u32)f2bf(b.y) << 16);
  u32 o3 = (u32)f2bf(b.z) | ((u32)f2bf(b.w) << 16);
  *(uint4*)(d + i) = make_uint4(o0, o1, o2, o3);
}

// ---------------- K1: 128x128 bf16 B^T GEMM, K=256 (ledger closed: 40.4us) ----
// XCD-aware swizzle: lb = (bid&7)*384 + bid>>3  (3072 wg / 8 XCDs)
__global__ __launch_bounds__(256) void gemm_qkv(
  const u16* __restrict__ A, const u16* __restrict__ Bm, char* __restrict__ outp)
{
  constexpr int K = 256;
  __shared__ __align__(16) char lds[65536];   // 2 bufs x (A 16KB + B 16KB)
  const int bid0 = blockIdx.x;
  const int bid = ((bid0 & 7) * 384) + (bid0 >> 3);
  const int tn = bid % 6, tm = bid / 6;
  const int m0 = tm * 128, n0 = tn * 128;
  const int tid  = threadIdx.x;
  const int lane = tid & 63, wid = tid >> 6;
  const int wm = (wid >> 1) * 64, wn = (wid & 1) * 64;
  const int l15 = lane & 15, l16 = lane >> 4;

  auto stage = [&](int buf, int kt){
    char* la = lds + buf * 32768;
    char* lb = la + 16384;
#pragma unroll
    for (int it = 0; it < 4; ++it){
      int ch  = it * 256 + tid;         // 16B chunk id
      int row = ch >> 3;
      int k8  = (ch & 7) ^ (row & 7);   // pre-swizzled global source (LDS linear)
      __builtin_amdgcn_global_load_lds(AS1(A  + (size_t)(m0 + row) * K + kt * 64 + k8 * 8),
                                       AS3(la + ch * 16), 16, 0, 0);
      __builtin_amdgcn_global_load_lds(AS1(Bm + (size_t)(n0 + row) * K + kt * 64 + k8 * 8),
                                       AS3(lb + ch * 16), 16, 0, 0);
    }
  };

  f32x4 acc[4][4];
#pragma unroll
  for (int i = 0; i < 4; ++i)
#pragma unroll
    for (int j = 0; j < 4; ++j) acc[i][j] = (f32x4){0.f, 0.f, 0.f, 0.f};

  stage(0, 0);
  __syncthreads();
  constexpr int NT = K / 64;
  for (int kt = 0; kt < NT; ++kt){
    const int buf = kt & 1;
    if (kt + 1 < NT) stage(buf ^ 1, kt + 1);
    const char* la = lds + buf * 32768;
    const char* lb = la + 16384;
#pragma unroll
    for (int kk = 0; kk < 2; ++kk){
      bf16x8 af[4], bfr[4];
      const int ka = kk * 4 + l16;
#pragma unroll
      for (int f = 0; f < 4; ++f){
        int ra = wm + f * 16 + l15;
        af[f]  = *(const bf16x8*)(la + ra * 128 + (((ka ^ ra) & 7) << 4));
        int rb = wn + f * 16 + l15;
        bfr[f] = *(const bf16x8*)(lb + rb * 128 + (((ka ^ rb) & 7) << 4));
      }
#pragma unroll
      for (int fm = 0; fm < 4; ++fm)
#pragma unroll
        for (int fn = 0; fn < 4; ++fn)
          acc[fm][fn] = __builtin_amdgcn_mfma_f32_16x16x32_bf16(bfr[fn], af[fm], acc[fm][fn], 0, 0, 0);
    }
    __syncthreads();
  }

  // swapped-C mapping: m = ...+l15, n = ...+l16*4+reg (4 consecutive n, 8B store)
#pragma unroll
  for (int fm = 0; fm < 4; ++fm)
#pragma unroll
    for (int fn = 0; fn < 4; ++fn){
      int m = m0 + wm + fm * 16 + l15;
      int n = n0 + wn + fn * 16 + l16 * 4;
      u32 lo = (u32)f2bf(acc[fm][fn][0]) | ((u32)f2bf(acc[fm][fn][1]) << 16);
      u32 hi = (u32)f2bf(acc[fm][fn][2]) | ((u32)f2bf(acc[fm][fn][3]) << 16);
      int s = n >> 8, hd = (n >> 5) & 7, cc = n & 31;
      int bb = m >> 12, tok = m & 4095;
      u16* dst = (u16*)(outp + (size_t)s * 33554432u);
      *(uint2*)(dst + ((size_t)(bb * 8 + hd) * 4096 + tok) * 32 + cc) = make_uint2(lo, hi);
    }
}

// ---------------- K2: per-(b,h) partial exp(k)^T v + denom, 16-way split ------
__global__ __launch_bounds__(256) void kv_partial(const u16* __restrict__ Kb, const u16* __restrict__ Vb,
                                                  float* __restrict__ pkv, float* __restrict__ pden){
  __shared__ float E [64][32];
  __shared__ float Vf[64][32];
  const int bh = blockIdx.x >> 4, sp = blockIdx.x & 15;
  const int tid = threadIdx.x;
  const u16* kp = Kb + ((size_t)bh * 4096 + sp * 256) * 32;
  const u16* vp = Vb + ((size_t)bh * 4096 + sp * 256) * 32;
  const int c = tid & 31, g = tid >> 5;
  const int srow = tid >> 2, scol = (tid & 3) * 8;
  float a0 = 0.f, a1 = 0.f, a2 = 0.f, a3 = 0.f, den = 0.f;
  for (int chx = 0; chx < 4; ++chx){
    uint4 kb4 = *(const uint4*)(kp + chx * 2048 + tid * 8);
    uint4 vb4 = *(const uint4*)(vp + chx * 2048 + tid * 8);
    float4 e0, e1, v0, v1;
    e0.x = __expf(bflo(kb4.x)); e0.y = __expf(bfhi(kb4.x));
    e0.z = __expf(bflo(kb4.y)); e0.w = __expf(bfhi(kb4.y));
    e1.x = __expf(bflo(kb4.z)); e1.y = __expf(bfhi(kb4.z));
    e1.z = __expf(bflo(kb4.w)); e1.w = __expf(bfhi(kb4.w));
    v0.x = bflo(vb4.x); v0.y = bfhi(vb4.x);
    v0.z = bflo(vb4.y); v0.w = bfhi(vb4.y);
    v1.x = bflo(vb4.z); v1.y = bfhi(vb4.z);
    v1.z = bflo(vb4.w); v1.w = bfhi(vb4.w);
    *(float4*)&E [srow][scol]     = e0;  *(float4*)&E [srow][scol + 4] = e1;
    *(float4*)&Vf[srow][scol]     = v0;  *(float4*)&Vf[srow][scol + 4] = v1;
    __syncthreads();
#pragma unroll 4
    for (int nn = 0; nn < 64; ++nn){
      float e = E[nn][c];
      float4 vv = *(const float4*)&Vf[nn][g * 4];
      a0 += e * vv.x; a1 += e * vv.y; a2 += e * vv.z; a3 += e * vv.w;
      den += e;
    }
    __syncthreads();
  }
  size_t base = ((size_t)sp * 128 + bh) * 1024 + (size_t)c * 32 + g * 4;
  *(float4*)&pkv[base] = make_float4(a0, a1, a2, a3);
  if (g == 0) pden[((size_t)sp * 128 + bh) * 32 + c] = den;
}

// ---------------- K3: reduce 16 splits + normalize + fold scale + build W2T ---
__global__ __launch_bounds__(256) void kv_w2(const float* __restrict__ pkv, const float* __restrict__ pden,
                                             const float* __restrict__ wproj, u16* __restrict__ w2t){
  __shared__ float kv[1024];
  __shared__ float dn[32];
  const int bh = blockIdx.x, b = bh >> 3, hd = bh & 7;
  const int t = threadIdx.x;
  if (t < 32){
    float d = 0.f;
#pragma unroll
    for (int s = 0; s < 16; ++s) d += pden[((size_t)s * 128 + bh) * 32 + t];
    dn[t] = 0.17677669529663687f / d;   // scale = 32^-0.5 folded
  }
  __syncthreads();
#pragma unroll
  for (int i = 0; i < 4; ++i){
    int idx = t + i * 256;
    float v = 0.f;
#pragma unroll
    for (int s = 0; s < 16; ++s) v += pkv[((size_t)s * 128 + bh) * 1024 + idx];
    kv[idx] = v * dn[idx >> 5];
  }
  __syncthreads();
  float wr[32];
  const float* wp = wproj + (size_t)t * 256 + hd * 32;
#pragma unroll
  for (int j = 0; j < 8; ++j){
    float4 w4 = ((const float4*)wp)[j];
    wr[j*4] = w4.x; wr[j*4+1] = w4.y; wr[j*4+2] = w4.z; wr[j*4+3] = w4.w;
  }
  u32 ou[16];
#pragma unroll
  for (int c = 0; c < 32; ++c){
    float acc = 0.f;
#pragma unroll
    for (int v4 = 0; v4 < 8; ++v4){
      float4 kk = *(const float4*)&kv[c * 32 + v4 * 4];   // uniform addr -> broadcast
      acc += kk.x * wr[v4*4] + kk.y * wr[v4*4+1] + kk.z * wr[v4*4+2] + kk.w * wr[v4*4+3];
    }
    if (c & 1) ou[c >> 1] |= (u32)f2bf(acc) << 16; else ou[c >> 1] = f2bf(acc);
  }
  uint4* dst = (uint4*)(w2t + (size_t)b * 65536 + (size_t)t * 256 + hd * 32);
  dst[0] = make_uint4(ou[0],  ou[1],  ou[2],  ou[3]);
  dst[1] = make_uint4(ou[4],  ou[5],  ou[6],  ou[7]);
  dst[2] = make_uint4(ou[8],  ou[9],  ou[10], ou[11]);
  dst[3] = make_uint4(ou[12], ou[13], ou[14], ou[15]);
}

// ---------------- K4: crpe = q * depthwise3x3(v), 8-row blocks (halo 10/8) ----
// 512 threads, 1024 blocks; staging 1.25x output (was 1.5x at 4 rows); LDS 42KB.
__global__ __launch_bounds__(512) void attn_crpe(const u16* __restrict__ Qb, const u16* __restrict__ Vb,
                                                 const float* __restrict__ cw, u16* __restrict__ tmp){
  __shared__ u16 VsB[10][66][32];  // 42240B: halo rows y0-1..y0+8, x 0..65 (pad=0)
  const int bid = blockIdx.x;
  const int bh = bid >> 3, rbk = bid & 7;
  const int y0 = rbk * 8;
  const int tid = threadIdx.x;
  const int x = tid & 63, yi = tid >> 6;   // yi in [0,8)
  const int n = (y0 + yi) * 64 + x;

  // staging: 10*66*4 = 2640 uint4 (8ch) chunks; 8ch XOR swizzle g8^=(xc>>1)&3
  for (int idx = tid; idx < 2640; idx += 512){
    int g8 = idx & 3, t2 = idx >> 2;
    int j  = t2 / 66, xc = t2 - j * 66;
    int gy = y0 - 1 + j, gx = xc - 1;
    uint4 v = make_uint4(0u, 0u, 0u, 0u);
    if ((unsigned)gy < 64u && (unsigned)gx < 64u)
      v = *(const uint4*)(Vb + ((size_t)bh * 4096 + gy * 64 + gx) * 32 + g8 * 8);
    *(uint4*)&VsB[j][xc][8 * (g8 ^ ((xc >> 1) & 3))] = v;
  }
  __syncthreads();

  // depthwise 3x3 conv; halo row j = yi + tap/3 (token row y0+yi = halo yi+1)
  float ca[32];
#pragma unroll
  for (int i = 0; i < 32; ++i) ca[i] = 0.f;
  const int hd = bh & 7;
  const float* wp = cw + hd * 288;
#pragma unroll
  for (int tap = 0; tap < 9; ++tap){
    const int j  = yi + tap / 3;
    const int xs = x + (tap % 3);
    const u16* vrow = &VsB[j][xs][0];
    const int swz = (xs >> 1) & 3;
#pragma unroll
    for (int g8 = 0; g8 < 4; ++g8){
      uint4 q4 = *(const uint4*)(vrow + 8 * (g8 ^ swz));
      const int c0 = g8 * 8;
      ca[c0+0] += wp[(c0+0)*9+tap] * bflo(q4.x);
      ca[c0+1] += wp[(c0+1)*9+tap] * bfhi(q4.x);
      ca[c0+2] += wp[(c0+2)*9+tap] * bflo(q4.y);
      ca[c0+3] += wp[(c0+3)*9+tap] * bfhi(q4.y);
      ca[c0+4] += wp[(c0+4)*9+tap] * bflo(q4.z);
      ca[c0+5] += wp[(c0+5)*9+tap] * bfhi(q4.z);
      ca[c0+6] += wp[(c0+6)*9+tap] * bflo(q4.w);
      ca[c0+7] += wp[(c0+7)*9+tap] * bfhi(q4.w);
    }
  }

  const u16* qrow = Qb + ((size_t)bh * 4096 + n) * 32;
  uint4 u0 = *(const uint4*)(qrow);
  uint4 u1 = *(const uint4*)(qrow + 8);
  uint4 u2 = *(const uint4*)(qrow + 16);
  uint4 u3 = *(const uint4*)(qrow + 24);
  float qf[32];
#define UQ(u, o) qf[o] = bflo(u); qf[(o)+1] = bfhi(u);
  UQ(u0.x, 0)  UQ(u0.y, 2)  UQ(u0.z, 4)  UQ(u0.w, 6)
  UQ(u1.x, 8)  UQ(u1.y, 10) UQ(u1.z, 12) UQ(u1.w, 14)
  UQ(u2.x, 16) UQ(u2.y, 18) UQ(u2.z, 20) UQ(u2.w, 22)
  UQ(u3.x, 24) UQ(u3.y, 26) UQ(u3.z, 28) UQ(u3.w, 30)
#undef UQ

  u32 ou[16];
#pragma unroll
  for (int p = 0; p < 16; ++p){
    float v0 = qf[2 * p]     * ca[2 * p];
    float v1 = qf[2 * p + 1] * ca[2 * p + 1];
    ou[p] = (u32)f2bf(v0) | ((u32)f2bf(v1) << 16);
  }
  uint4* dst = (uint4*)(tmp + ((size_t)bh * 4096 + n) * 32);   // plane layout
  dst[0] = make_uint4(ou[0],  ou[1],  ou[2],  ou[3]);
  dst[1] = make_uint4(ou[4],  ou[5],  ou[6],  ou[7]);
  dst[2] = make_uint4(ou[8],  ou[9],  ou[10], ou[11]);
  dst[3] = make_uint4(ou[12], ou[13], ou[14], ou[15]);
}

// ---------------- K5: final GEMM, K=512: out = [crpe | q] @ [Wp^T ; W2[b]] + bias
// XCD-aware swizzle: lb = (bid&7)*128 + bid>>3  (1024 wg / 8 XCDs)
__global__ __launch_bounds__(256) void gemm_fin(
  const u16* __restrict__ Acr, const u16* __restrict__ Qb,
  const u16* __restrict__ Bw,  const u16* __restrict__ W2t,
  float* __restrict__ outp, const float* __restrict__ bias)
{
  __shared__ __align__(16) char lds[65536];
  const int bid0 = blockIdx.x;
  const int bid = ((bid0 & 7) * 128) + (bid0 >> 3);
  const int tn = bid & 1, tm = bid >> 1;
  const int m0 = tm * 128, n0 = tn * 128;
  const int b = m0 >> 12, nbase = m0 & 4095;
  const int tid  = threadIdx.x;
  const int lane = tid & 63, wid = tid >> 6;
  const int wm = (wid >> 1) * 64, wn = (wid & 1) * 64;
  const int l15 = lane & 15, l16 = lane >> 4;

  auto stage = [&](int buf, int kt){
    char* la = lds + buf * 32768;
    char* lb = la + 16384;
#pragma unroll
    for (int it = 0; it < 4; ++it){
      int ch  = it * 256 + tid;
      int row = ch >> 3;
      int k8  = (ch & 7) ^ (row & 7);
      int kp  = kt * 64 + k8 * 8;         // 0..511
      const u16* pl = (kp < 256) ? Acr : Qb;
      int kq = kp & 255, hd = kq >> 5, cc = kq & 31;
      const u16* asrc = pl + ((size_t)(b * 8 + hd) * 4096 + (nbase + row)) * 32 + cc;
      const u16* bsrc = (kp < 256)
        ? Bw  + (size_t)(n0 + row) * 256 + kp
        : W2t + (size_t)b * 65536 + (size_t)(n0 + row) * 256 + (kp - 256);
      __builtin_amdgcn_global_load_lds(AS1(asrc), AS3(la + ch * 16), 16, 0, 0);
      __builtin_amdgcn_global_load_lds(AS1(bsrc), AS3(lb + ch * 16), 16, 0, 0);
    }
  };

  f32x4 acc[4][4];
#pragma unroll
  for (int i = 0; i < 4; ++i)
#pragma unroll
    for (int j = 0; j < 4; ++j) acc[i][j] = (f32x4){0.f, 0.f, 0.f, 0.f};

  stage(0, 0);
  __syncthreads();
  constexpr int NT = 8;   // K = 512
  for (int kt = 0; kt < NT; ++kt){
    const int buf = kt & 1;
    if (kt + 1 < NT) stage(buf ^ 1, kt + 1);
    const char* la = lds + buf * 32768;
    const char* lb = la + 16384;
#pragma unroll
    for (int kk = 0; kk < 2; ++kk){
      bf16x8 af[4], bfr[4];
      const int ka = kk * 4 + l16;
#pragma unroll
      for (int f = 0; f < 4; ++f){
        int ra = wm + f * 16 + l15;
        af[f]  = *(const bf16x8*)(la + ra * 128 + (((ka ^ ra) & 7) << 4));
        int rb = wn + f * 16 + l15;
        bfr[f] = *(const bf16x8*)(lb + rb * 128 + (((ka ^ rb) & 7) << 4));
      }
#pragma unroll
      for (int fm = 0; fm < 4; ++fm)
#pragma unroll
        for (int fn = 0; fn < 4; ++fn)
          acc[fm][fn] = __builtin_amdgcn_mfma_f32_16x16x32_bf16(af[fm], bfr[fn], acc[fm][fn], 0, 0, 0);
    }
    __syncthreads();
  }

#pragma unroll
  for (int fm = 0; fm < 4; ++fm)
#pragma unroll
    for (int fn = 0; fn < 4; ++fn)
#pragma unroll
      for (int r = 0; r < 4; ++r){
        int m = m0 + wm + fm * 16 + l16 * 4 + r;
        int n = n0 + wn + fn * 16 + l15;
        outp[(size_t)m * 256 + n] = acc[fm][fn][r] + bias[n];
      }
}

// ---------------- launch ----------------
// ws (~111.4 MB): Qb[0,32M) Kb[32M,64M) Vb[64M,96M) wprojb(128K) pkv(8M) pden(256K) w2t(2M)
// d_out scratch: xbf(32M)@0, wqkvb(384K)@32M — both dead before gemm_fin writes d_out.
// crpe tmp aliases Kb (plane layout; K dead after kv_partial).
extern "C" void kernel_launch(void* const* d_in, const int* in_sizes, int n_in,
                              void* d_out, int out_size, void* d_ws, size_t ws_size,
                              hipStream_t stream) {
  const float* x      = (const float*)d_in[0];
  const float* w_qkv  = (const float*)d_in[1];
  const float* w_proj = (const float*)d_in[2];
  const float* b_proj = (const float*)d_in[3];
  const float* conv_w = (const float*)d_in[4];

  char* ws = (char*)d_ws;
  char* ob = (char*)d_out;

  char*  qkvb   =          ws;
  u16*   Qb     = (u16*)  (ws);
  u16*   Kb     = (u16*)  (ws + 33554432);
  u16*   Vb     = (u16*)  (ws + 67108864);
  u16*   wprojb = (u16*)  (ws + 100663296);     // 128KB
  float* pkv    = (float*)(ws + 100794368);     // 8MB
  float* pden   = (float*)(ws + 109182976);     // 256KB
  u16*   w2t    = (u16*)  (ws + 109445120);     // 2MB -> ends ~111.4MB

  u16*   xbf    = (u16*)  (ob);                 // 32MB scratch in d_out
  u16*   wqkvb  = (u16*)  (ob + 33554432);      // 384KB scratch in d_out
  u16*   tmp    = Kb;                           // crpe plane; K dead after kv_partial

  cvt_all<<<8320, 256, 0, stream>>>(x, xbf, w_qkv, wqkvb, w_proj, wprojb);

  gemm_qkv<<<3072, 256, 0, stream>>>(xbf, wqkvb, qkvb);

  kv_partial<<<2048, 256, 0, stream>>>(Kb, Vb, pkv, pden);
  kv_w2<<<128, 256, 0, stream>>>(pkv, pden, w_proj, w2t);

  attn_crpe<<<1024, 512, 0, stream>>>(Qb, Vb, conv_w, tmp);

  gemm_fin<<<1024, 256, 0, stream>>>(tmp, Qb, wprojb, w2t, (float*)d_out, b_proj);
}